// Round 8
// baseline (287.307 us; speedup 1.0000x reference)
//
#include <hip/hip_runtime.h>
#include <hip/hip_fp16.h>
#include <math.h>

#define N_NODES 50000
#define N_EDGES 800000
#define N_GRAPHS 512
#define SCAN_NB 196                       // ceil(50000/256)
#define SENT N_NODES
#define RE_NB 3125                        // reorder blocks (800000/256)

// workspace byte offsets — every table 256B-aligned; fp16 rows = exactly 1 line
#define OFF_HIST    0u                    // 50000 ints
#define OFF_DINV    200192u               // 50000 floats
#define OFF_OFFS    400384u               // 50001 ints
#define OFF_CURSOR  600576u               // 50000 ints
#define OFF_BSUM    800768u               // 256 ints
#define OFF_BOFF    801792u               // 256 ints
#define OFF_SORTED  803840u               // 1150000 ints (800k + 50k*7 pad-8)
#define OFF_XSH1    5403904u              // 50001*64 halves
#define OFF_XSH2    11804160u             // 50001*64 halves
#define OFF_HBUF    18204416u             // 50000*64 fp32 (h1, reused as h2)

// ---- histogram of dst ----
__global__ __launch_bounds__(256) void prep(const int* __restrict__ dst, int* __restrict__ hist) {
    int e = blockIdx.x * 256 + threadIdx.x;
    if (e < N_EDGES) atomicAdd(&hist[dst[e]], 1);
}

// ---- scan phase 1 ----
__global__ __launch_bounds__(256) void scan1(const int* __restrict__ hist, int* __restrict__ offs,
                                             int* __restrict__ bsum, float* __restrict__ dinv) {
    __shared__ int sh[256];
    int t = threadIdx.x;
    int i = blockIdx.x * 256 + t;
    int v = (i < N_NODES) ? hist[i] : 0;
    int pv = (v + 7) & ~7;
    if (i < N_NODES) dinv[i] = rsqrtf(1.0f + (float)v);
    sh[t] = pv;
    __syncthreads();
    for (int d = 1; d < 256; d <<= 1) {
        int add = (t >= d) ? sh[t - d] : 0;
        __syncthreads();
        sh[t] += add;
        __syncthreads();
    }
    if (i < N_NODES) offs[i] = sh[t] - pv;
    if (t == 255) bsum[blockIdx.x] = sh[255];
}

// ---- scan phase 2 ----
__global__ __launch_bounds__(256) void scan2(const int* __restrict__ bsum, int* __restrict__ boff) {
    __shared__ int sh[256];
    int t = threadIdx.x;
    int v = (t < SCAN_NB) ? bsum[t] : 0;
    sh[t] = v;
    __syncthreads();
    for (int d = 1; d < 256; d <<= 1) {
        int add = (t >= d) ? sh[t - d] : 0;
        __syncthreads();
        sh[t] += add;
        __syncthreads();
    }
    if (t < SCAN_NB) boff[t] = sh[t] - v;
}

// ---- scan phase 3: globalize offsets; cursor; pad sentinels; zero sentinel rows ----
__global__ __launch_bounds__(256) void scan3(int* __restrict__ offs, const int* __restrict__ boff,
                                             int* __restrict__ cursor, const int* __restrict__ hist,
                                             int* __restrict__ sorted,
                                             unsigned short* __restrict__ xsh1,
                                             unsigned short* __restrict__ xsh2) {
    int i = blockIdx.x * 256 + threadIdx.x;
    if (i < N_NODES) {
        int deg = hist[i];
        int o = offs[i] + boff[blockIdx.x];
        offs[i] = o;
        cursor[i] = o;
        int pd = (deg + 7) & ~7;
        for (int p = o + deg; p < o + pd; ++p) sorted[p] = SENT;
        if (i == N_NODES - 1) offs[N_NODES] = o + pd;
    } else {
        int r = i - N_NODES;
        if (r < 64) xsh1[N_NODES * 64 + r] = 0;
        else if (r < 128) xsh2[N_NODES * 64 + (r - 64)] = 0;
    }
}

// ---- combo: blocks [0,RE_NB) scatter edges; blocks [RE_NB,2*RE_NB) do layer-1 GEMM ----
__global__ __launch_bounds__(256) void combo(const int* __restrict__ src, const int* __restrict__ dst,
                                             int* __restrict__ cursor, int* __restrict__ sorted,
                                             const float* __restrict__ X, const float* __restrict__ W,
                                             const float* __restrict__ dinv, __half* __restrict__ xsh) {
    __shared__ float sW[128 * 64];
    __shared__ float sX[16 * 132];
    int bid = blockIdx.x;
    int tid = threadIdx.x;
    if (bid < RE_NB) {                     // ---- reorder (atomic/memory-bound) ----
        int e = bid * 256 + tid;           // 800000 == RE_NB*256 exact
        int d = dst[e];
        int p = atomicAdd(&cursor[d], 1);
        sorted[p] = src[e];
        return;
    }
    // ---- gemm1 (VALU-bound), runs concurrent with reorder ----
    int row0 = (bid - RE_NB) * 16;         // 50000/16 == RE_NB
    {
        const float4* ws = (const float4*)W;
        float4* wd = (float4*)sW;
        for (int i = tid; i < 2048; i += 256) wd[i] = ws[i];
        const float4* xs = (const float4*)(X + row0 * 128);
        for (int i = tid; i < 512; i += 256) {
            int r = i >> 5, q = i & 31;
            *(float4*)&sX[r * 132 + 4 * q] = xs[r * 32 + q];
        }
    }
    __syncthreads();
    int r = tid >> 4;
    int cg = (tid & 15) * 4;
    int row = row0 + r;
    float a0 = 0, a1 = 0, a2 = 0, a3 = 0;
#pragma unroll 8
    for (int k = 0; k < 128; ++k) {
        float xv = sX[r * 132 + k];
        float4 w = *(const float4*)&sW[k * 64 + cg];
        a0 += xv * w.x; a1 += xv * w.y; a2 += xv * w.z; a3 += xv * w.w;
    }
    float s = dinv[row];
    __half2 lo = __floats2half2_rn(a0 * s, a1 * s);
    __half2 hi = __floats2half2_rn(a2 * s, a3 * s);
    uint2 pk;
    pk.x = *(const unsigned int*)&lo;
    pk.y = *(const unsigned int*)&hi;
    *(uint2*)&xsh[row * 64 + cg] = pk;
}

// ---- GEMM layer 2: xsh2 = fp16((h1 @ W2) * dinv[row]), K=64 ----
__global__ __launch_bounds__(256) void gemm2(const float* __restrict__ X, const float* __restrict__ W,
                                             const float* __restrict__ dinv, __half* __restrict__ xsh) {
    __shared__ float sW[64 * 64];
    __shared__ float sX[16][65];
    int tid = threadIdx.x;
    for (int i = tid; i < 64 * 64; i += 256) sW[i] = W[i];
    int row0 = blockIdx.x * 16;
    for (int i = tid; i < 16 * 64; i += 256) {
        int r = i >> 6, k = i & 63;
        sX[r][k] = X[(row0 + r) * 64 + k];
    }
    __syncthreads();
    int r = tid >> 4;
    int cg = (tid & 15) * 4;
    int row = row0 + r;
    float a0 = 0, a1 = 0, a2 = 0, a3 = 0;
#pragma unroll 8
    for (int k = 0; k < 64; ++k) {
        float xv = sX[r][k];
        float4 w = *(const float4*)&sW[k * 64 + cg];
        a0 += xv * w.x; a1 += xv * w.y; a2 += xv * w.z; a3 += xv * w.w;
    }
    float s = dinv[row];
    __half2 lo = __floats2half2_rn(a0 * s, a1 * s);
    __half2 hi = __floats2half2_rn(a2 * s, a3 * s);
    uint2 pk;
    pk.x = *(const unsigned int*)&lo;
    pk.y = *(const unsigned int*)&hi;
    *(uint2*)&xsh[row * 64 + cg] = pk;
}

// ---- multi-node streaming gather: wave owns 4 consecutive nodes; groups stream
//      with a 4-deep pipeline across node boundaries; flush = reduce + store ----
#define ADD_ROW(rv) { \
    const __half2* ph = (const __half2*)&(rv); \
    float2 f0 = __half22float2(ph[0]), f1 = __half22float2(ph[1]); \
    float2 f2 = __half22float2(ph[2]), f3 = __half22float2(ph[3]); \
    a0 += f0.x; a1 += f0.y; a2 += f1.x; a3 += f1.y; \
    a4 += f2.x; a5 += f2.y; a6 += f3.x; a7 += f3.y; }

__global__ __launch_bounds__(256) void gather_m(const __half* __restrict__ xsh,
                                                const int* __restrict__ offs,
                                                const int* __restrict__ sorted,
                                                const float* __restrict__ dinv,
                                                const float* __restrict__ bias,
                                                float* __restrict__ fout) {
    int wv = blockIdx.x * 4 + (threadIdx.x >> 6);  // 3125*4 waves, 4 nodes each
    int lane = threadIdx.x & 63;
    int sub = lane >> 3, frag = lane & 7;
    int n0 = wv * 4;
    int ov = offs[n0 + (lane < 5 ? lane : 4)];
    int e0 = __shfl(ov, 0), e1 = __shfl(ov, 1), e2 = __shfl(ov, 2);
    int e3 = __shfl(ov, 3), e4 = __shfl(ov, 4);
    int G   = (e4 - e0) >> 3;
    int nb1 = (e1 - e0) >> 3, nb2 = (e2 - e0) >> 3, nb3 = (e3 - e0) >> 3;
    const int* sb = sorted + e0 + sub;
    int i0 = (0 < G) ? sb[0]  : SENT;
    int i1 = (1 < G) ? sb[8]  : SENT;
    int i2 = (2 < G) ? sb[16] : SENT;
    int i3 = (3 < G) ? sb[24] : SENT;
    float4 bA = *(const float4*)(bias + frag * 8);
    float4 bB = *(const float4*)(bias + frag * 8 + 4);
    int cur = 0;
    uint4 sv = *(const uint4*)(xsh + n0 * 64 + frag * 8);
    float dv = dinv[n0];
    float a0 = 0, a1 = 0, a2 = 0, a3 = 0, a4 = 0, a5 = 0, a6 = 0, a7 = 0;

#define FLUSH_ADV() { \
    if (sub == 0) ADD_ROW(sv); \
    a0 += __shfl_xor(a0, 8);  a1 += __shfl_xor(a1, 8);  a2 += __shfl_xor(a2, 8);  a3 += __shfl_xor(a3, 8); \
    a4 += __shfl_xor(a4, 8);  a5 += __shfl_xor(a5, 8);  a6 += __shfl_xor(a6, 8);  a7 += __shfl_xor(a7, 8); \
    a0 += __shfl_xor(a0, 16); a1 += __shfl_xor(a1, 16); a2 += __shfl_xor(a2, 16); a3 += __shfl_xor(a3, 16); \
    a4 += __shfl_xor(a4, 16); a5 += __shfl_xor(a5, 16); a6 += __shfl_xor(a6, 16); a7 += __shfl_xor(a7, 16); \
    a0 += __shfl_xor(a0, 32); a1 += __shfl_xor(a1, 32); a2 += __shfl_xor(a2, 32); a3 += __shfl_xor(a3, 32); \
    a4 += __shfl_xor(a4, 32); a5 += __shfl_xor(a5, 32); a6 += __shfl_xor(a6, 32); a7 += __shfl_xor(a7, 32); \
    if (sub == 0) { \
        float4 w0, w1; \
        w0.x = fmaxf(a0 * dv + bA.x, 0.0f); w0.y = fmaxf(a1 * dv + bA.y, 0.0f); \
        w0.z = fmaxf(a2 * dv + bA.z, 0.0f); w0.w = fmaxf(a3 * dv + bA.w, 0.0f); \
        w1.x = fmaxf(a4 * dv + bB.x, 0.0f); w1.y = fmaxf(a5 * dv + bB.y, 0.0f); \
        w1.z = fmaxf(a6 * dv + bB.z, 0.0f); w1.w = fmaxf(a7 * dv + bB.w, 0.0f); \
        float* o = fout + (n0 + cur) * 64 + frag * 8; \
        *(float4*)(o) = w0; *(float4*)(o + 4) = w1; \
    } \
    a0 = a1 = a2 = a3 = a4 = a5 = a6 = a7 = 0.0f; \
    cur++; \
    if (cur < 4) { \
        sv = *(const uint4*)(xsh + (n0 + cur) * 64 + frag * 8); \
        dv = dinv[n0 + cur]; \
    } }

#define BND_NXT() (cur == 0 ? nb1 : cur == 1 ? nb2 : cur == 2 ? nb3 : G)

    for (int g = 0; g < G; g += 4) {
        uint4 r0 = *(const uint4*)(xsh + i0 * 64 + frag * 8);
        uint4 r1 = *(const uint4*)(xsh + i1 * 64 + frag * 8);
        uint4 r2 = *(const uint4*)(xsh + i2 * 64 + frag * 8);
        uint4 r3 = *(const uint4*)(xsh + i3 * 64 + frag * 8);
        const int* np = sb + (g + 4) * 8;
        i0 = (g + 4 < G) ? np[0]  : SENT;
        i1 = (g + 5 < G) ? np[8]  : SENT;
        i2 = (g + 6 < G) ? np[16] : SENT;
        i3 = (g + 7 < G) ? np[24] : SENT;
        {   int gg = g;
            int nxt = BND_NXT();
            while (cur < 4 && gg >= nxt) { FLUSH_ADV(); nxt = BND_NXT(); }
            ADD_ROW(r0); }
        if (g + 1 < G) {
            int gg = g + 1;
            int nxt = BND_NXT();
            while (cur < 4 && gg >= nxt) { FLUSH_ADV(); nxt = BND_NXT(); }
            ADD_ROW(r1);
        }
        if (g + 2 < G) {
            int gg = g + 2;
            int nxt = BND_NXT();
            while (cur < 4 && gg >= nxt) { FLUSH_ADV(); nxt = BND_NXT(); }
            ADD_ROW(r2);
        }
        if (g + 3 < G) {
            int gg = g + 3;
            int nxt = BND_NXT();
            while (cur < 4 && gg >= nxt) { FLUSH_ADV(); nxt = BND_NXT(); }
            ADD_ROW(r3);
        }
    }
    while (cur < 4) { FLUSH_ADV(); }
#undef FLUSH_ADV
#undef BND_NXT
}

// ---- fused pool (segmented mean over sorted batch) + fc head + log_softmax ----
__device__ __forceinline__ int lower_bound(const int* __restrict__ a, int n, int v) {
    int lo = 0, hi = n;
    while (lo < hi) { int m = (lo + hi) >> 1; if (a[m] < v) lo = m + 1; else hi = m; }
    return lo;
}

__global__ __launch_bounds__(256) void pool_head(const float* __restrict__ h2,
                                                 const int* __restrict__ batch,
                                                 const float* __restrict__ Wfc, const float* __restrict__ bfc,
                                                 const int* __restrict__ y, float* __restrict__ out) {
    __shared__ int s_beg, s_end;
    __shared__ float sh[4][64];
    __shared__ float pl[64];
    __shared__ float lg[4];
    int g = blockIdx.x;
    int t = threadIdx.x;
    if (t == 0) s_beg = lower_bound(batch, N_NODES, g);
    if (t == 1) s_end = lower_bound(batch, N_NODES, g + 1);
    __syncthreads();
    int beg = s_beg, end = s_end;
    int f = t & 63, seg = t >> 6;
    float s = 0.0f;
    for (int r = beg + seg; r < end; r += 4) s += h2[r * 64 + f];
    sh[seg][f] = s;
    __syncthreads();
    if (t < 64) {
        float p = sh[0][t] + sh[1][t] + sh[2][t] + sh[3][t];
        pl[t] = p / fmaxf((float)(end - beg), 1.0f);
    }
    __syncthreads();
    if (t < 4) {
        float l = bfc[t];
#pragma unroll
        for (int k = 0; k < 64; ++k) l += pl[k] * Wfc[k * 4 + t];
        lg[t] = l;
    }
    __syncthreads();
    if (t == 0) {
        float l0 = lg[0], l1 = lg[1], l2 = lg[2], l3 = lg[3];
        float m = fmaxf(fmaxf(l0, l1), fmaxf(l2, l3));
        float ss = expf(l0 - m) + expf(l1 - m) + expf(l2 - m) + expf(l3 - m);
        float lse = m + logf(ss);
        out[g * 4 + 0] = l0 - lse;
        out[g * 4 + 1] = l1 - lse;
        out[g * 4 + 2] = l2 - lse;
        out[g * 4 + 3] = l3 - lse;
        out[N_GRAPHS * 4 + g] = (float)y[g];
    }
}

extern "C" void kernel_launch(void* const* d_in, const int* in_sizes, int n_in,
                              void* d_out, int out_size, void* d_ws, size_t ws_size,
                              hipStream_t stream) {
    const float* x     = (const float*)d_in[0];
    const int*   ei    = (const int*)d_in[1];
    const int*   batch = (const int*)d_in[2];
    const int*   y     = (const int*)d_in[3];
    const float* W1    = (const float*)d_in[4];
    const float* b1    = (const float*)d_in[5];
    const float* W2    = (const float*)d_in[6];
    const float* b2    = (const float*)d_in[7];
    const float* Wfc   = (const float*)d_in[8];
    const float* bfc   = (const float*)d_in[9];
    float* out = (float*)d_out;

    const int* src = ei;
    const int* dst = ei + N_EDGES;

    char* wsb = (char*)d_ws;
    int*    hist   = (int*)(wsb + OFF_HIST);
    float*  dinv   = (float*)(wsb + OFF_DINV);
    int*    offs   = (int*)(wsb + OFF_OFFS);
    int*    cursor = (int*)(wsb + OFF_CURSOR);
    int*    bsum   = (int*)(wsb + OFF_BSUM);
    int*    boff   = (int*)(wsb + OFF_BOFF);
    int*    sorted = (int*)(wsb + OFF_SORTED);
    __half* xsh1   = (__half*)(wsb + OFF_XSH1);
    __half* xsh2   = (__half*)(wsb + OFF_XSH2);
    float*  hbuf   = (float*)(wsb + OFF_HBUF);   // h1, later reused as h2

    hipMemsetAsync(hist, 0, 200000u, stream);

    prep<<<(N_EDGES + 255) / 256, 256, 0, stream>>>(dst, hist);
    scan1<<<SCAN_NB, 256, 0, stream>>>(hist, offs, bsum, dinv);
    scan2<<<1, 256, 0, stream>>>(bsum, boff);
    scan3<<<SCAN_NB, 256, 0, stream>>>(offs, boff, cursor, hist, sorted,
                                       (unsigned short*)xsh1, (unsigned short*)xsh2);

    // reorder (atomic-bound) and gemm1 (VALU-bound) run concurrently
    combo<<<2 * RE_NB, 256, 0, stream>>>(src, dst, cursor, sorted, x, W1, dinv, xsh1);

    // layer 1 aggregate + relu -> h1
    gather_m<<<RE_NB, 256, 0, stream>>>(xsh1, offs, sorted, dinv, b1, hbuf);
    // layer 2 GEMM
    gemm2<<<N_NODES / 16, 256, 0, stream>>>(hbuf, W2, dinv, xsh2);
    // layer 2 aggregate + relu -> h2 (reuse hbuf)
    gather_m<<<RE_NB, 256, 0, stream>>>(xsh2, offs, sorted, dinv, b2, hbuf);

    pool_head<<<N_GRAPHS, 256, 0, stream>>>(hbuf, batch, Wfc, bfc, y, out);
}

// Round 9
// 275.174 us; speedup vs baseline: 1.0441x; 1.0441x over previous
//
#include <hip/hip_runtime.h>
#include <hip/hip_fp16.h>
#include <math.h>

#define N_NODES 50000
#define N_EDGES 800000
#define N_GRAPHS 512
#define SCAN_NB 196                       // ceil(50000/256)
#define SENT N_NODES
#define RE_NB 3125                        // 800000/256

typedef float v2f __attribute__((ext_vector_type(2)));

// workspace byte offsets — tables 256B-aligned; fp8 rows = 64B (2 rows/line)
#define OFF_HIST    0u                    // 50000 ints
#define OFF_DINV    200192u               // 50000 floats
#define OFF_OFFS    400384u               // 50001 ints
#define OFF_CURSOR  600576u               // 50000 ints
#define OFF_BSUM    800768u               // 256 ints
#define OFF_BOFF    801792u               // 256 ints
#define OFF_SORTED  803840u               // 1150000 ints (800k + 50k*7 pad-8)
#define OFF_XS8_1   5403904u              // 50001*64 bytes fp8
#define OFF_XS8_2   8604160u              // 50001*64 bytes fp8
#define OFF_HBUF    11804416u             // 50000*64 fp32 (h1, reused as h2)

// ---- histogram of dst ----
__global__ __launch_bounds__(256) void prep(const int* __restrict__ dst, int* __restrict__ hist) {
    int e = blockIdx.x * 256 + threadIdx.x;
    if (e < N_EDGES) atomicAdd(&hist[dst[e]], 1);
}

// ---- scan phase 1 ----
__global__ __launch_bounds__(256) void scan1(const int* __restrict__ hist, int* __restrict__ offs,
                                             int* __restrict__ bsum, float* __restrict__ dinv) {
    __shared__ int sh[256];
    int t = threadIdx.x;
    int i = blockIdx.x * 256 + t;
    int v = (i < N_NODES) ? hist[i] : 0;
    int pv = (v + 7) & ~7;
    if (i < N_NODES) dinv[i] = rsqrtf(1.0f + (float)v);
    sh[t] = pv;
    __syncthreads();
    for (int d = 1; d < 256; d <<= 1) {
        int add = (t >= d) ? sh[t - d] : 0;
        __syncthreads();
        sh[t] += add;
        __syncthreads();
    }
    if (i < N_NODES) offs[i] = sh[t] - pv;
    if (t == 255) bsum[blockIdx.x] = sh[255];
}

// ---- scan phase 2 ----
__global__ __launch_bounds__(256) void scan2(const int* __restrict__ bsum, int* __restrict__ boff) {
    __shared__ int sh[256];
    int t = threadIdx.x;
    int v = (t < SCAN_NB) ? bsum[t] : 0;
    sh[t] = v;
    __syncthreads();
    for (int d = 1; d < 256; d <<= 1) {
        int add = (t >= d) ? sh[t - d] : 0;
        __syncthreads();
        sh[t] += add;
        __syncthreads();
    }
    if (t < SCAN_NB) boff[t] = sh[t] - v;
}

// ---- scan phase 3: globalize offsets; cursor; pad sentinels; zero sentinel rows ----
__global__ __launch_bounds__(256) void scan3(int* __restrict__ offs, const int* __restrict__ boff,
                                             int* __restrict__ cursor, const int* __restrict__ hist,
                                             int* __restrict__ sorted,
                                             unsigned int* __restrict__ x1,
                                             unsigned int* __restrict__ x2) {
    int i = blockIdx.x * 256 + threadIdx.x;
    if (i < N_NODES) {
        int deg = hist[i];
        int o = offs[i] + boff[blockIdx.x];
        offs[i] = o;
        cursor[i] = o;
        int pd = (deg + 7) & ~7;
        for (int p = o + deg; p < o + pd; ++p) sorted[p] = SENT;
        if (i == N_NODES - 1) offs[N_NODES] = o + pd;
    } else {
        int r = i - N_NODES;               // zero sentinel row 50000 (16 uints each table)
        if (r < 16) x1[N_NODES * 16 + r] = 0;
        else if (r < 32) x2[N_NODES * 16 + (r - 16)] = 0;
    }
}

// ---- reorder edges into padded dst-buckets ----
__global__ __launch_bounds__(256) void reorder(const int* __restrict__ src, const int* __restrict__ dst,
                                               int* __restrict__ cursor, int* __restrict__ sorted, int n) {
    int e = blockIdx.x * 256 + threadIdx.x;
    if (e < n) {
        int d = dst[e];
        int p = atomicAdd(&cursor[d], 1);
        sorted[p] = src[e];
    }
}

// ---- GEMM layer 1: xs8 = fp8((X @ W1) * dinv[row]), K=128 ----
__global__ __launch_bounds__(256) void gemm1(const float* __restrict__ X, const float* __restrict__ W,
                                             const float* __restrict__ dinv, unsigned int* __restrict__ xs8) {
    __shared__ float sW[128 * 64];
    __shared__ float sX[16 * 132];
    int tid = threadIdx.x;
    {
        const float4* ws = (const float4*)W;
        float4* wd = (float4*)sW;
        for (int i = tid; i < 2048; i += 256) wd[i] = ws[i];
    }
    int row0 = blockIdx.x * 16;
    {
        const float4* xs = (const float4*)(X + row0 * 128);
        for (int i = tid; i < 512; i += 256) {
            int r = i >> 5, q = i & 31;
            *(float4*)&sX[r * 132 + 4 * q] = xs[r * 32 + q];
        }
    }
    __syncthreads();
    int r = tid >> 4;
    int cg = (tid & 15) * 4;
    int row = row0 + r;
    float a0 = 0, a1 = 0, a2 = 0, a3 = 0;
#pragma unroll 8
    for (int k = 0; k < 128; ++k) {
        float xv = sX[r * 132 + k];
        float4 w = *(const float4*)&sW[k * 64 + cg];
        a0 += xv * w.x; a1 += xv * w.y; a2 += xv * w.z; a3 += xv * w.w;
    }
    float s = dinv[row];
    unsigned int pk = 0;
    pk = __builtin_amdgcn_cvt_pk_fp8_f32(a0 * s, a1 * s, pk, false);
    pk = __builtin_amdgcn_cvt_pk_fp8_f32(a2 * s, a3 * s, pk, true);
    xs8[row * 16 + (cg >> 2)] = pk;
}

// ---- GEMM layer 2: xs8 = fp8((h1 @ W2) * dinv[row]), K=64 ----
__global__ __launch_bounds__(256) void gemm2(const float* __restrict__ X, const float* __restrict__ W,
                                             const float* __restrict__ dinv, unsigned int* __restrict__ xs8) {
    __shared__ float sW[64 * 64];
    __shared__ float sX[16][65];
    int tid = threadIdx.x;
    for (int i = tid; i < 64 * 64; i += 256) sW[i] = W[i];
    int row0 = blockIdx.x * 16;
    for (int i = tid; i < 16 * 64; i += 256) {
        int r = i >> 6, k = i & 63;
        sX[r][k] = X[(row0 + r) * 64 + k];
    }
    __syncthreads();
    int r = tid >> 4;
    int cg = (tid & 15) * 4;
    int row = row0 + r;
    float a0 = 0, a1 = 0, a2 = 0, a3 = 0;
#pragma unroll 8
    for (int k = 0; k < 64; ++k) {
        float xv = sX[r][k];
        float4 w = *(const float4*)&sW[k * 64 + cg];
        a0 += xv * w.x; a1 += xv * w.y; a2 += xv * w.z; a3 += xv * w.w;
    }
    float s = dinv[row];
    unsigned int pk = 0;
    pk = __builtin_amdgcn_cvt_pk_fp8_f32(a0 * s, a1 * s, pk, false);
    pk = __builtin_amdgcn_cvt_pk_fp8_f32(a2 * s, a3 * s, pk, true);
    xs8[row * 16 + (cg >> 2)] = pk;
}

// ---- multi-node streaming gather (fp8 rows, 64B each) ----
#define ADD_ROW(rv) { \
    v2f f0 = __builtin_amdgcn_cvt_pk_f32_fp8((rv).x, false); \
    v2f f1 = __builtin_amdgcn_cvt_pk_f32_fp8((rv).x, true); \
    v2f f2 = __builtin_amdgcn_cvt_pk_f32_fp8((rv).y, false); \
    v2f f3 = __builtin_amdgcn_cvt_pk_f32_fp8((rv).y, true); \
    a0 += f0.x; a1 += f0.y; a2 += f1.x; a3 += f1.y; \
    a4 += f2.x; a5 += f2.y; a6 += f3.x; a7 += f3.y; }

__global__ __launch_bounds__(256) void gather_m(const unsigned char* __restrict__ xs8,
                                                const int* __restrict__ offs,
                                                const int* __restrict__ sorted,
                                                const float* __restrict__ dinv,
                                                const float* __restrict__ bias,
                                                float* __restrict__ fout) {
    int wv = blockIdx.x * 4 + (threadIdx.x >> 6);  // 12500 waves, 4 nodes each
    int lane = threadIdx.x & 63;
    int sub = lane >> 3, frag = lane & 7;
    int n0 = wv * 4;
    int ov = offs[n0 + (lane < 5 ? lane : 4)];
    int e0 = __shfl(ov, 0), e1 = __shfl(ov, 1), e2 = __shfl(ov, 2);
    int e3 = __shfl(ov, 3), e4 = __shfl(ov, 4);
    int G   = (e4 - e0) >> 3;
    int nb1 = (e1 - e0) >> 3, nb2 = (e2 - e0) >> 3, nb3 = (e3 - e0) >> 3;
    const int* sb = sorted + e0 + sub;
    int i0 = (0 < G) ? sb[0]  : SENT;
    int i1 = (1 < G) ? sb[8]  : SENT;
    int i2 = (2 < G) ? sb[16] : SENT;
    int i3 = (3 < G) ? sb[24] : SENT;
    float4 bA = *(const float4*)(bias + frag * 8);
    float4 bB = *(const float4*)(bias + frag * 8 + 4);
    int cur = 0;
    uint2 sv = *(const uint2*)(xs8 + n0 * 64 + frag * 8);
    float dv = dinv[n0];
    float a0 = 0, a1 = 0, a2 = 0, a3 = 0, a4 = 0, a5 = 0, a6 = 0, a7 = 0;

#define FLUSH_ADV() { \
    if (sub == 0) ADD_ROW(sv); \
    a0 += __shfl_xor(a0, 8);  a1 += __shfl_xor(a1, 8);  a2 += __shfl_xor(a2, 8);  a3 += __shfl_xor(a3, 8); \
    a4 += __shfl_xor(a4, 8);  a5 += __shfl_xor(a5, 8);  a6 += __shfl_xor(a6, 8);  a7 += __shfl_xor(a7, 8); \
    a0 += __shfl_xor(a0, 16); a1 += __shfl_xor(a1, 16); a2 += __shfl_xor(a2, 16); a3 += __shfl_xor(a3, 16); \
    a4 += __shfl_xor(a4, 16); a5 += __shfl_xor(a5, 16); a6 += __shfl_xor(a6, 16); a7 += __shfl_xor(a7, 16); \
    a0 += __shfl_xor(a0, 32); a1 += __shfl_xor(a1, 32); a2 += __shfl_xor(a2, 32); a3 += __shfl_xor(a3, 32); \
    a4 += __shfl_xor(a4, 32); a5 += __shfl_xor(a5, 32); a6 += __shfl_xor(a6, 32); a7 += __shfl_xor(a7, 32); \
    if (sub == 0) { \
        float4 w0, w1; \
        w0.x = fmaxf(a0 * dv + bA.x, 0.0f); w0.y = fmaxf(a1 * dv + bA.y, 0.0f); \
        w0.z = fmaxf(a2 * dv + bA.z, 0.0f); w0.w = fmaxf(a3 * dv + bA.w, 0.0f); \
        w1.x = fmaxf(a4 * dv + bB.x, 0.0f); w1.y = fmaxf(a5 * dv + bB.y, 0.0f); \
        w1.z = fmaxf(a6 * dv + bB.z, 0.0f); w1.w = fmaxf(a7 * dv + bB.w, 0.0f); \
        float* o = fout + (n0 + cur) * 64 + frag * 8; \
        *(float4*)(o) = w0; *(float4*)(o + 4) = w1; \
    } \
    a0 = a1 = a2 = a3 = a4 = a5 = a6 = a7 = 0.0f; \
    cur++; \
    if (cur < 4) { \
        sv = *(const uint2*)(xs8 + (n0 + cur) * 64 + frag * 8); \
        dv = dinv[n0 + cur]; \
    } }

#define BND_NXT() (cur == 0 ? nb1 : cur == 1 ? nb2 : cur == 2 ? nb3 : G)

    for (int g = 0; g < G; g += 4) {
        uint2 r0 = *(const uint2*)(xs8 + i0 * 64 + frag * 8);
        uint2 r1 = *(const uint2*)(xs8 + i1 * 64 + frag * 8);
        uint2 r2 = *(const uint2*)(xs8 + i2 * 64 + frag * 8);
        uint2 r3 = *(const uint2*)(xs8 + i3 * 64 + frag * 8);
        const int* np = sb + (g + 4) * 8;
        i0 = (g + 4 < G) ? np[0]  : SENT;
        i1 = (g + 5 < G) ? np[8]  : SENT;
        i2 = (g + 6 < G) ? np[16] : SENT;
        i3 = (g + 7 < G) ? np[24] : SENT;
        {   int gg = g;
            int nxt = BND_NXT();
            while (cur < 4 && gg >= nxt) { FLUSH_ADV(); nxt = BND_NXT(); }
            ADD_ROW(r0); }
        if (g + 1 < G) {
            int gg = g + 1;
            int nxt = BND_NXT();
            while (cur < 4 && gg >= nxt) { FLUSH_ADV(); nxt = BND_NXT(); }
            ADD_ROW(r1);
        }
        if (g + 2 < G) {
            int gg = g + 2;
            int nxt = BND_NXT();
            while (cur < 4 && gg >= nxt) { FLUSH_ADV(); nxt = BND_NXT(); }
            ADD_ROW(r2);
        }
        if (g + 3 < G) {
            int gg = g + 3;
            int nxt = BND_NXT();
            while (cur < 4 && gg >= nxt) { FLUSH_ADV(); nxt = BND_NXT(); }
            ADD_ROW(r3);
        }
    }
    while (cur < 4) { FLUSH_ADV(); }
#undef FLUSH_ADV
#undef BND_NXT
}

// ---- fused pool (segmented mean over sorted batch) + fc head + log_softmax ----
__device__ __forceinline__ int lower_bound(const int* __restrict__ a, int n, int v) {
    int lo = 0, hi = n;
    while (lo < hi) { int m = (lo + hi) >> 1; if (a[m] < v) lo = m + 1; else hi = m; }
    return lo;
}

__global__ __launch_bounds__(256) void pool_head(const float* __restrict__ h2,
                                                 const int* __restrict__ batch,
                                                 const float* __restrict__ Wfc, const float* __restrict__ bfc,
                                                 const int* __restrict__ y, float* __restrict__ out) {
    __shared__ int s_beg, s_end;
    __shared__ float sh[4][64];
    __shared__ float pl[64];
    __shared__ float lg[4];
    int g = blockIdx.x;
    int t = threadIdx.x;
    if (t == 0) s_beg = lower_bound(batch, N_NODES, g);
    if (t == 1) s_end = lower_bound(batch, N_NODES, g + 1);
    __syncthreads();
    int beg = s_beg, end = s_end;
    int f = t & 63, seg = t >> 6;
    float s = 0.0f;
    for (int r = beg + seg; r < end; r += 4) s += h2[r * 64 + f];
    sh[seg][f] = s;
    __syncthreads();
    if (t < 64) {
        float p = sh[0][t] + sh[1][t] + sh[2][t] + sh[3][t];
        pl[t] = p / fmaxf((float)(end - beg), 1.0f);
    }
    __syncthreads();
    if (t < 4) {
        float l = bfc[t];
#pragma unroll
        for (int k = 0; k < 64; ++k) l += pl[k] * Wfc[k * 4 + t];
        lg[t] = l;
    }
    __syncthreads();
    if (t == 0) {
        float l0 = lg[0], l1 = lg[1], l2 = lg[2], l3 = lg[3];
        float m = fmaxf(fmaxf(l0, l1), fmaxf(l2, l3));
        float ss = expf(l0 - m) + expf(l1 - m) + expf(l2 - m) + expf(l3 - m);
        float lse = m + logf(ss);
        out[g * 4 + 0] = l0 - lse;
        out[g * 4 + 1] = l1 - lse;
        out[g * 4 + 2] = l2 - lse;
        out[g * 4 + 3] = l3 - lse;
        out[N_GRAPHS * 4 + g] = (float)y[g];
    }
}

extern "C" void kernel_launch(void* const* d_in, const int* in_sizes, int n_in,
                              void* d_out, int out_size, void* d_ws, size_t ws_size,
                              hipStream_t stream) {
    const float* x     = (const float*)d_in[0];
    const int*   ei    = (const int*)d_in[1];
    const int*   batch = (const int*)d_in[2];
    const int*   y     = (const int*)d_in[3];
    const float* W1    = (const float*)d_in[4];
    const float* b1    = (const float*)d_in[5];
    const float* W2    = (const float*)d_in[6];
    const float* b2    = (const float*)d_in[7];
    const float* Wfc   = (const float*)d_in[8];
    const float* bfc   = (const float*)d_in[9];
    float* out = (float*)d_out;

    const int* src = ei;
    const int* dst = ei + N_EDGES;

    char* wsb = (char*)d_ws;
    int*          hist   = (int*)(wsb + OFF_HIST);
    float*        dinv   = (float*)(wsb + OFF_DINV);
    int*          offs   = (int*)(wsb + OFF_OFFS);
    int*          cursor = (int*)(wsb + OFF_CURSOR);
    int*          bsum   = (int*)(wsb + OFF_BSUM);
    int*          boff   = (int*)(wsb + OFF_BOFF);
    int*          sorted = (int*)(wsb + OFF_SORTED);
    unsigned int* xs8_1  = (unsigned int*)(wsb + OFF_XS8_1);
    unsigned int* xs8_2  = (unsigned int*)(wsb + OFF_XS8_2);
    float*        hbuf   = (float*)(wsb + OFF_HBUF);

    hipMemsetAsync(hist, 0, 200000u, stream);

    prep<<<(N_EDGES + 255) / 256, 256, 0, stream>>>(dst, hist);
    scan1<<<SCAN_NB, 256, 0, stream>>>(hist, offs, bsum, dinv);
    scan2<<<1, 256, 0, stream>>>(bsum, boff);
    scan3<<<SCAN_NB, 256, 0, stream>>>(offs, boff, cursor, hist, sorted, xs8_1, xs8_2);
    reorder<<<RE_NB, 256, 0, stream>>>(src, dst, cursor, sorted, N_EDGES);

    // layer 1: 128 -> 64
    gemm1<<<N_NODES / 16, 256, 0, stream>>>(x, W1, dinv, xs8_1);
    gather_m<<<RE_NB, 256, 0, stream>>>((const unsigned char*)xs8_1, offs, sorted, dinv, b1, hbuf);
    // layer 2: 64 -> 64
    gemm2<<<N_NODES / 16, 256, 0, stream>>>(hbuf, W2, dinv, xs8_2);
    gather_m<<<RE_NB, 256, 0, stream>>>((const unsigned char*)xs8_2, offs, sorted, dinv, b2, hbuf);

    pool_head<<<N_GRAPHS, 256, 0, stream>>>(hbuf, batch, Wfc, bfc, y, out);
}

// Round 11
// 246.935 us; speedup vs baseline: 1.1635x; 1.1144x over previous
//
#include <hip/hip_runtime.h>
#include <hip/hip_fp16.h>
#include <math.h>

#define N_NODES 50000
#define N_EDGES 800000
#define N_GRAPHS 512
#define SCAN_NB 196                       // ceil(50000/256) == bucket count
#define SENT N_NODES
#define RE_NB 3125                        // 800000/256

typedef float v2f __attribute__((ext_vector_type(2)));

// workspace byte offsets — big tables 256B-aligned; fp8 rows = 64B (2 rows/line)
#define OFF_HIST    0u                    // 50000 ints
#define OFF_DINV    200192u               // 50000 floats
#define OFF_OFFS    400384u               // 50001 ints
#define OFF_UBOFF   600576u               // 197 ints
#define OFF_BCUR    601600u               // 196 ints
#define OFF_BSUM    602624u               // 256 ints
#define OFF_UBSUM   603648u               // 256 ints
#define OFF_BOFF    604672u               // 256 ints
#define OFF_SORTED  605696u               // 1150000 ints (800k + 50k*7 pad-8)
#define OFF_TMP     5205760u              // 800000 uints (binned staging)
#define OFF_XS8_1   8405760u              // 50001*64 bytes fp8
#define OFF_XS8_2   11606016u             // 50001*64 bytes fp8
#define OFF_HBUF    14806272u             // 50000*64 fp32 (h1, reused as h2)

// ---- histogram of dst ----
__global__ __launch_bounds__(256) void prep(const int* __restrict__ dst, int* __restrict__ hist) {
    int e = blockIdx.x * 256 + threadIdx.x;
    if (e < N_EDGES) atomicAdd(&hist[dst[e]], 1);
}

// ---- scan phase 1: padded (offs) and unpadded (bucket) block scans; dinv ----
__global__ __launch_bounds__(256) void scan1(const int* __restrict__ hist, int* __restrict__ offs,
                                             int* __restrict__ bsum, int* __restrict__ ubsum,
                                             float* __restrict__ dinv) {
    __shared__ int shP[256], shU[256];
    int t = threadIdx.x;
    int i = blockIdx.x * 256 + t;
    int v = (i < N_NODES) ? hist[i] : 0;
    int pv = (v + 7) & ~7;
    if (i < N_NODES) dinv[i] = rsqrtf(1.0f + (float)v);
    shP[t] = pv; shU[t] = v;
    __syncthreads();
    for (int d = 1; d < 256; d <<= 1) {
        int aP = (t >= d) ? shP[t - d] : 0;
        int aU = (t >= d) ? shU[t - d] : 0;
        __syncthreads();
        shP[t] += aP; shU[t] += aU;
        __syncthreads();
    }
    if (i < N_NODES) offs[i] = shP[t] - pv;
    if (t == 255) { bsum[blockIdx.x] = shP[255]; ubsum[blockIdx.x] = shU[255]; }
}

// ---- scan phase 2: scan block sums (padded + unpadded); init bucket cursors ----
__global__ __launch_bounds__(256) void scan2(const int* __restrict__ bsum, const int* __restrict__ ubsum,
                                             int* __restrict__ boff, int* __restrict__ uboff,
                                             int* __restrict__ bcur) {
    __shared__ int shP[256], shU[256];
    int t = threadIdx.x;
    int vP = (t < SCAN_NB) ? bsum[t] : 0;
    int vU = (t < SCAN_NB) ? ubsum[t] : 0;
    shP[t] = vP; shU[t] = vU;
    __syncthreads();
    for (int d = 1; d < 256; d <<= 1) {
        int aP = (t >= d) ? shP[t - d] : 0;
        int aU = (t >= d) ? shU[t - d] : 0;
        __syncthreads();
        shP[t] += aP; shU[t] += aU;
        __syncthreads();
    }
    if (t < SCAN_NB) {
        boff[t] = shP[t] - vP;
        int u = shU[t] - vU;
        uboff[t] = u;
        bcur[t] = u;
    }
    if (t == 0) uboff[SCAN_NB] = N_EDGES;
}

// ---- scan phase 3: globalize offsets; zero fp8 sentinel rows ----
__global__ __launch_bounds__(256) void scan3(int* __restrict__ offs, const int* __restrict__ boff,
                                             const int* __restrict__ hist,
                                             unsigned int* __restrict__ x1,
                                             unsigned int* __restrict__ x2) {
    int i = blockIdx.x * 256 + threadIdx.x;
    if (i < N_NODES) {
        int o = offs[i] + boff[blockIdx.x];
        offs[i] = o;
        if (i == N_NODES - 1) offs[N_NODES] = o + ((hist[i] + 7) & ~7);
    } else {
        int r = i - N_NODES;               // zero sentinel row 50000 (16 uints each table)
        if (r < 16) x1[N_NODES * 16 + r] = 0;
        else if (r < 32) x2[N_NODES * 16 + (r - 16)] = 0;
    }
}

// ---- binA: bin edges into per-bucket contiguous runs (bucket = dst>>8) ----
__global__ __launch_bounds__(256) void binA(const int* __restrict__ src, const int* __restrict__ dst,
                                            int* __restrict__ bcur, unsigned int* __restrict__ tmp) {
    __shared__ int cnt[SCAN_NB], base[SCAN_NB], cnt2[SCAN_NB];
    int t = threadIdx.x;
    for (int j = t; j < SCAN_NB; j += 256) { cnt[j] = 0; cnt2[j] = 0; }
    __syncthreads();
    int e0 = blockIdx.x * 4096;
    int sA[16], dA[16];
#pragma unroll
    for (int i = 0; i < 16; ++i) {
        int e = e0 + i * 256 + t;
        if (e < N_EDGES) {
            sA[i] = src[e];
            dA[i] = dst[e];
            atomicAdd(&cnt[dA[i] >> 8], 1);
        } else dA[i] = -1;
    }
    __syncthreads();
    for (int j = t; j < SCAN_NB; j += 256)
        base[j] = cnt[j] ? atomicAdd(&bcur[j], cnt[j]) : 0;
    __syncthreads();
#pragma unroll
    for (int i = 0; i < 16; ++i) {
        if (dA[i] >= 0) {
            int b = dA[i] >> 8;
            int pos = base[b] + atomicAdd(&cnt2[b], 1);
            tmp[pos] = (unsigned int)sA[i] | ((unsigned int)(dA[i] & 255) << 17);  // src < 2^17
        }
    }
}

// ---- binB: one block per bucket; LDS cursors; dense window scatter + pad fill ----
__global__ __launch_bounds__(256) void binB(const unsigned int* __restrict__ tmp,
                                            const int* __restrict__ uboff, const int* __restrict__ offs,
                                            int* __restrict__ sorted) {
    __shared__ int cur[256];
    int b = blockIdx.x, t = threadIdx.x;
    int nb0 = b * 256;
    int nc = N_NODES - nb0; if (nc > 256) nc = 256;
    if (t < nc) cur[t] = offs[nb0 + t];
    __syncthreads();
    int ub0 = uboff[b], ub1 = uboff[b + 1];
    for (int e = ub0 + t; e < ub1; e += 256) {
        unsigned int pk = tmp[e];
        int p = atomicAdd(&cur[pk >> 17], 1);
        sorted[p] = (int)(pk & 0x1FFFFu);
    }
    __syncthreads();
    if (t < nc) {
        int pend = offs[nb0 + t + 1];
        for (int p = cur[t]; p < pend; ++p) sorted[p] = SENT;
    }
}

// ---- GEMM layer 1: xs8 = fp8((X @ W1) * dinv[row]), K=128 ----
__global__ __launch_bounds__(256) void gemm1(const float* __restrict__ X, const float* __restrict__ W,
                                             const float* __restrict__ dinv, unsigned int* __restrict__ xs8) {
    __shared__ float sW[128 * 64];
    __shared__ float sX[16 * 132];
    int tid = threadIdx.x;
    {
        const float4* ws = (const float4*)W;
        float4* wd = (float4*)sW;
        for (int i = tid; i < 2048; i += 256) wd[i] = ws[i];
    }
    int row0 = blockIdx.x * 16;
    {
        const float4* xs = (const float4*)(X + row0 * 128);
        for (int i = tid; i < 512; i += 256) {
            int r = i >> 5, q = i & 31;
            *(float4*)&sX[r * 132 + 4 * q] = xs[r * 32 + q];
        }
    }
    __syncthreads();
    int r = tid >> 4;
    int cg = (tid & 15) * 4;
    int row = row0 + r;
    float a0 = 0, a1 = 0, a2 = 0, a3 = 0;
#pragma unroll 8
    for (int k = 0; k < 128; ++k) {
        float xv = sX[r * 132 + k];
        float4 w = *(const float4*)&sW[k * 64 + cg];
        a0 += xv * w.x; a1 += xv * w.y; a2 += xv * w.z; a3 += xv * w.w;
    }
    float s = dinv[row];
    unsigned int pk = 0;
    pk = __builtin_amdgcn_cvt_pk_fp8_f32(a0 * s, a1 * s, pk, false);
    pk = __builtin_amdgcn_cvt_pk_fp8_f32(a2 * s, a3 * s, pk, true);
    xs8[row * 16 + (cg >> 2)] = pk;
}

// ---- GEMM layer 2: xs8 = fp8((h1 @ W2) * dinv[row]), K=64 ----
__global__ __launch_bounds__(256) void gemm2(const float* __restrict__ X, const float* __restrict__ W,
                                             const float* __restrict__ dinv, unsigned int* __restrict__ xs8) {
    __shared__ float sW[64 * 64];
    __shared__ float sX[16][65];
    int tid = threadIdx.x;
    for (int i = tid; i < 64 * 64; i += 256) sW[i] = W[i];
    int row0 = blockIdx.x * 16;
    for (int i = tid; i < 16 * 64; i += 256) {
        int r = i >> 6, k = i & 63;
        sX[r][k] = X[(row0 + r) * 64 + k];
    }
    __syncthreads();
    int r = tid >> 4;
    int cg = (tid & 15) * 4;
    int row = row0 + r;
    float a0 = 0, a1 = 0, a2 = 0, a3 = 0;
#pragma unroll 8
    for (int k = 0; k < 64; ++k) {
        float xv = sX[r][k];
        float4 w = *(const float4*)&sW[k * 64 + cg];
        a0 += xv * w.x; a1 += xv * w.y; a2 += xv * w.z; a3 += xv * w.w;
    }
    float s = dinv[row];
    unsigned int pk = 0;
    pk = __builtin_amdgcn_cvt_pk_fp8_f32(a0 * s, a1 * s, pk, false);
    pk = __builtin_amdgcn_cvt_pk_fp8_f32(a2 * s, a3 * s, pk, true);
    xs8[row * 16 + (cg >> 2)] = pk;
}

// ---- multi-node streaming gather (fp8 rows, 64B each) ----
#define ADD_ROW(rv) { \
    v2f f0 = __builtin_amdgcn_cvt_pk_f32_fp8((rv).x, false); \
    v2f f1 = __builtin_amdgcn_cvt_pk_f32_fp8((rv).x, true); \
    v2f f2 = __builtin_amdgcn_cvt_pk_f32_fp8((rv).y, false); \
    v2f f3 = __builtin_amdgcn_cvt_pk_f32_fp8((rv).y, true); \
    a0 += f0.x; a1 += f0.y; a2 += f1.x; a3 += f1.y; \
    a4 += f2.x; a5 += f2.y; a6 += f3.x; a7 += f3.y; }

__global__ __launch_bounds__(256) void gather_m(const unsigned char* __restrict__ xs8,
                                                const int* __restrict__ offs,
                                                const int* __restrict__ sorted,
                                                const float* __restrict__ dinv,
                                                const float* __restrict__ bias,
                                                float* __restrict__ fout) {
    int wv = blockIdx.x * 4 + (threadIdx.x >> 6);  // 12500 waves, 4 nodes each
    int lane = threadIdx.x & 63;
    int sub = lane >> 3, frag = lane & 7;
    int n0 = wv * 4;
    int ov = offs[n0 + (lane < 5 ? lane : 4)];
    int e0 = __shfl(ov, 0), e1 = __shfl(ov, 1), e2 = __shfl(ov, 2);
    int e3 = __shfl(ov, 3), e4 = __shfl(ov, 4);
    int G   = (e4 - e0) >> 3;
    int nb1 = (e1 - e0) >> 3, nb2 = (e2 - e0) >> 3, nb3 = (e3 - e0) >> 3;
    const int* sb = sorted + e0 + sub;
    int i0 = (0 < G) ? sb[0]  : SENT;
    int i1 = (1 < G) ? sb[8]  : SENT;
    int i2 = (2 < G) ? sb[16] : SENT;
    int i3 = (3 < G) ? sb[24] : SENT;
    float4 bA = *(const float4*)(bias + frag * 8);
    float4 bB = *(const float4*)(bias + frag * 8 + 4);
    int cur = 0;
    uint2 sv = *(const uint2*)(xs8 + n0 * 64 + frag * 8);
    float dv = dinv[n0];
    float a0 = 0, a1 = 0, a2 = 0, a3 = 0, a4 = 0, a5 = 0, a6 = 0, a7 = 0;

#define FLUSH_ADV() { \
    if (sub == 0) ADD_ROW(sv); \
    a0 += __shfl_xor(a0, 8);  a1 += __shfl_xor(a1, 8);  a2 += __shfl_xor(a2, 8);  a3 += __shfl_xor(a3, 8); \
    a4 += __shfl_xor(a4, 8);  a5 += __shfl_xor(a5, 8);  a6 += __shfl_xor(a6, 8);  a7 += __shfl_xor(a7, 8); \
    a0 += __shfl_xor(a0, 16); a1 += __shfl_xor(a1, 16); a2 += __shfl_xor(a2, 16); a3 += __shfl_xor(a3, 16); \
    a4 += __shfl_xor(a4, 16); a5 += __shfl_xor(a5, 16); a6 += __shfl_xor(a6, 16); a7 += __shfl_xor(a7, 16); \
    a0 += __shfl_xor(a0, 32); a1 += __shfl_xor(a1, 32); a2 += __shfl_xor(a2, 32); a3 += __shfl_xor(a3, 32); \
    a4 += __shfl_xor(a4, 32); a5 += __shfl_xor(a5, 32); a6 += __shfl_xor(a6, 32); a7 += __shfl_xor(a7, 32); \
    if (sub == 0) { \
        float4 w0, w1; \
        w0.x = fmaxf(a0 * dv + bA.x, 0.0f); w0.y = fmaxf(a1 * dv + bA.y, 0.0f); \
        w0.z = fmaxf(a2 * dv + bA.z, 0.0f); w0.w = fmaxf(a3 * dv + bA.w, 0.0f); \
        w1.x = fmaxf(a4 * dv + bB.x, 0.0f); w1.y = fmaxf(a5 * dv + bB.y, 0.0f); \
        w1.z = fmaxf(a6 * dv + bB.z, 0.0f); w1.w = fmaxf(a7 * dv + bB.w, 0.0f); \
        float* o = fout + (n0 + cur) * 64 + frag * 8; \
        *(float4*)(o) = w0; *(float4*)(o + 4) = w1; \
    } \
    a0 = a1 = a2 = a3 = a4 = a5 = a6 = a7 = 0.0f; \
    cur++; \
    if (cur < 4) { \
        sv = *(const uint2*)(xs8 + (n0 + cur) * 64 + frag * 8); \
        dv = dinv[n0 + cur]; \
    } }

#define BND_NXT() (cur == 0 ? nb1 : cur == 1 ? nb2 : cur == 2 ? nb3 : G)

    for (int g = 0; g < G; g += 4) {
        uint2 r0 = *(const uint2*)(xs8 + i0 * 64 + frag * 8);
        uint2 r1 = *(const uint2*)(xs8 + i1 * 64 + frag * 8);
        uint2 r2 = *(const uint2*)(xs8 + i2 * 64 + frag * 8);
        uint2 r3 = *(const uint2*)(xs8 + i3 * 64 + frag * 8);
        const int* np = sb + (g + 4) * 8;
        i0 = (g + 4 < G) ? np[0]  : SENT;
        i1 = (g + 5 < G) ? np[8]  : SENT;
        i2 = (g + 6 < G) ? np[16] : SENT;
        i3 = (g + 7 < G) ? np[24] : SENT;
        {   int gg = g;
            int nxt = BND_NXT();
            while (cur < 4 && gg >= nxt) { FLUSH_ADV(); nxt = BND_NXT(); }
            ADD_ROW(r0); }
        if (g + 1 < G) {
            int gg = g + 1;
            int nxt = BND_NXT();
            while (cur < 4 && gg >= nxt) { FLUSH_ADV(); nxt = BND_NXT(); }
            ADD_ROW(r1);
        }
        if (g + 2 < G) {
            int gg = g + 2;
            int nxt = BND_NXT();
            while (cur < 4 && gg >= nxt) { FLUSH_ADV(); nxt = BND_NXT(); }
            ADD_ROW(r2);
        }
        if (g + 3 < G) {
            int gg = g + 3;
            int nxt = BND_NXT();
            while (cur < 4 && gg >= nxt) { FLUSH_ADV(); nxt = BND_NXT(); }
            ADD_ROW(r3);
        }
    }
    while (cur < 4) { FLUSH_ADV(); }
#undef FLUSH_ADV
#undef BND_NXT
}

// ---- fused pool (segmented mean over sorted batch) + fc head + log_softmax ----
__device__ __forceinline__ int lower_bound(const int* __restrict__ a, int n, int v) {
    int lo = 0, hi = n;
    while (lo < hi) { int m = (lo + hi) >> 1; if (a[m] < v) lo = m + 1; else hi = m; }
    return lo;
}

__global__ __launch_bounds__(256) void pool_head(const float* __restrict__ h2,
                                                 const int* __restrict__ batch,
                                                 const float* __restrict__ Wfc, const float* __restrict__ bfc,
                                                 const int* __restrict__ y, float* __restrict__ out) {
    __shared__ int s_beg, s_end;
    __shared__ float sh[4][64];
    __shared__ float pl[64];
    __shared__ float lg[4];
    int g = blockIdx.x;
    int t = threadIdx.x;
    if (t == 0) s_beg = lower_bound(batch, N_NODES, g);
    if (t == 1) s_end = lower_bound(batch, N_NODES, g + 1);
    __syncthreads();
    int beg = s_beg, end = s_end;
    int f = t & 63, seg = t >> 6;
    float s = 0.0f;
    for (int r = beg + seg; r < end; r += 4) s += h2[r * 64 + f];
    sh[seg][f] = s;
    __syncthreads();
    if (t < 64) {
        float p = sh[0][t] + sh[1][t] + sh[2][t] + sh[3][t];
        pl[t] = p / fmaxf((float)(end - beg), 1.0f);
    }
    __syncthreads();
    if (t < 4) {
        float l = bfc[t];
#pragma unroll
        for (int k = 0; k < 64; ++k) l += pl[k] * Wfc[k * 4 + t];
        lg[t] = l;
    }
    __syncthreads();
    if (t == 0) {
        float l0 = lg[0], l1 = lg[1], l2 = lg[2], l3 = lg[3];
        float m = fmaxf(fmaxf(l0, l1), fmaxf(l2, l3));
        float ss = expf(l0 - m) + expf(l1 - m) + expf(l2 - m) + expf(l3 - m);
        float lse = m + logf(ss);
        out[g * 4 + 0] = l0 - lse;
        out[g * 4 + 1] = l1 - lse;
        out[g * 4 + 2] = l2 - lse;
        out[g * 4 + 3] = l3 - lse;
        out[N_GRAPHS * 4 + g] = (float)y[g];
    }
}

extern "C" void kernel_launch(void* const* d_in, const int* in_sizes, int n_in,
                              void* d_out, int out_size, void* d_ws, size_t ws_size,
                              hipStream_t stream) {
    const float* x     = (const float*)d_in[0];
    const int*   ei    = (const int*)d_in[1];
    const int*   batch = (const int*)d_in[2];
    const int*   y     = (const int*)d_in[3];
    const float* W1    = (const float*)d_in[4];
    const float* b1    = (const float*)d_in[5];
    const float* W2    = (const float*)d_in[6];
    const float* b2    = (const float*)d_in[7];
    const float* Wfc   = (const float*)d_in[8];
    const float* bfc   = (const float*)d_in[9];
    float* out = (float*)d_out;

    const int* src = ei;
    const int* dst = ei + N_EDGES;

    char* wsb = (char*)d_ws;
    int*          hist   = (int*)(wsb + OFF_HIST);
    float*        dinv   = (float*)(wsb + OFF_DINV);
    int*          offs   = (int*)(wsb + OFF_OFFS);
    int*          uboff  = (int*)(wsb + OFF_UBOFF);
    int*          bcur   = (int*)(wsb + OFF_BCUR);
    int*          bsum   = (int*)(wsb + OFF_BSUM);
    int*          ubsum  = (int*)(wsb + OFF_UBSUM);
    int*          boff   = (int*)(wsb + OFF_BOFF);
    int*          sorted = (int*)(wsb + OFF_SORTED);
    unsigned int* tmp    = (unsigned int*)(wsb + OFF_TMP);
    unsigned int* xs8_1  = (unsigned int*)(wsb + OFF_XS8_1);
    unsigned int* xs8_2  = (unsigned int*)(wsb + OFF_XS8_2);
    float*        hbuf   = (float*)(wsb + OFF_HBUF);

    hipMemsetAsync(hist, 0, 200000u, stream);

    prep<<<RE_NB, 256, 0, stream>>>(dst, hist);
    scan1<<<SCAN_NB, 256, 0, stream>>>(hist, offs, bsum, ubsum, dinv);
    scan2<<<1, 256, 0, stream>>>(bsum, ubsum, boff, uboff, bcur);
    scan3<<<SCAN_NB, 256, 0, stream>>>(offs, boff, hist, xs8_1, xs8_2);
    binA<<<SCAN_NB, 256, 0, stream>>>(src, dst, bcur, tmp);
    binB<<<SCAN_NB, 256, 0, stream>>>(tmp, uboff, offs, sorted);

    // layer 1: 128 -> 64
    gemm1<<<N_NODES / 16, 256, 0, stream>>>(x, W1, dinv, xs8_1);
    gather_m<<<RE_NB, 256, 0, stream>>>((const unsigned char*)xs8_1, offs, sorted, dinv, b1, hbuf);
    // layer 2: 64 -> 64
    gemm2<<<N_NODES / 16, 256, 0, stream>>>(hbuf, W2, dinv, xs8_2);
    gather_m<<<RE_NB, 256, 0, stream>>>((const unsigned char*)xs8_2, offs, sorted, dinv, b2, hbuf);

    pool_head<<<N_GRAPHS, 256, 0, stream>>>(hbuf, batch, Wfc, bfc, y, out);
}

// Round 12
// 210.244 us; speedup vs baseline: 1.3665x; 1.1745x over previous
//
#include <hip/hip_runtime.h>
#include <hip/hip_fp16.h>
#include <math.h>

#define N_NODES 50000
#define N_EDGES 800000
#define N_GRAPHS 512
#define NBKT 196                          // ceil(50000/256) buckets
#define SENT N_NODES
#define CAP_T 6144                        // tmp slots/bucket (mean 4096, sd 64 -> 32 sd)
#define CAP_S 8192                        // sorted slots/bucket (padded max 7936)

typedef float v2f __attribute__((ext_vector_type(2)));

// workspace byte offsets (256B-aligned)
#define OFF_BCNT    0u                    // 196 ints (zeroed by memset)
#define OFF_DINV    1024u                 // 50000 floats
#define OFF_OFFS2   201216u               // 50000 int2
#define OFF_TMP     601344u               // 196*6144 uints
#define OFF_SORTED  5418240u              // 196*8192 ints
#define OFF_XS8_1   11840768u             // 50001*64 bytes fp8
#define OFF_XS8_2   15041024u             // 50001*64 bytes fp8
#define OFF_HBUF    18241280u             // 50000*64 fp32

// ---- binA: bin edges into fixed-capacity bucket runs (bucket = dst>>8) ----
__global__ __launch_bounds__(256) void binA(const int* __restrict__ src, const int* __restrict__ dst,
                                            int* __restrict__ bcnt, unsigned int* __restrict__ tmp,
                                            unsigned int* __restrict__ x1, unsigned int* __restrict__ x2) {
    __shared__ int cnt[NBKT], base[NBKT], cnt2[NBKT];
    int t = threadIdx.x;
    for (int j = t; j < NBKT; j += 256) { cnt[j] = 0; cnt2[j] = 0; }
    if (blockIdx.x == 0) {                 // zero fp8 sentinel row 50000 of both tables
        if (t < 16) x1[N_NODES * 16 + t] = 0;
        else if (t < 32) x2[N_NODES * 16 + (t - 16)] = 0;
    }
    __syncthreads();
    int e0 = blockIdx.x * 4096;
    int sA[16], dA[16];
#pragma unroll
    for (int i = 0; i < 16; ++i) {
        int e = e0 + i * 256 + t;
        if (e < N_EDGES) {
            sA[i] = src[e];
            dA[i] = dst[e];
            atomicAdd(&cnt[dA[i] >> 8], 1);
        } else dA[i] = -1;
    }
    __syncthreads();
    for (int j = t; j < NBKT; j += 256)
        base[j] = cnt[j] ? atomicAdd(&bcnt[j], cnt[j]) : 0;
    __syncthreads();
#pragma unroll
    for (int i = 0; i < 16; ++i) {
        if (dA[i] >= 0) {
            int b = dA[i] >> 8;
            int pos = base[b] + atomicAdd(&cnt2[b], 1);
            tmp[b * CAP_T + pos] = (unsigned int)sA[i] | ((unsigned int)(dA[i] & 255) << 17);  // src < 2^17
        }
    }
}

// ---- binB2: per bucket — LDS histogram + scan -> offs2/dinv; scatter; pad fill ----
__global__ __launch_bounds__(256) void binB2(const unsigned int* __restrict__ tmp,
                                             const int* __restrict__ bcnt,
                                             int* __restrict__ sorted, int2* __restrict__ offs2,
                                             float* __restrict__ dinv) {
    __shared__ int cnt[256];
    __shared__ int scn[256];
    __shared__ int cur[256];
    int b = blockIdx.x, t = threadIdx.x;
    cnt[t] = 0;
    __syncthreads();
    int m = bcnt[b];
    const unsigned int* tp = tmp + b * CAP_T;
    for (int e = t; e < m; e += 256) atomicAdd(&cnt[tp[e] >> 17], 1);
    __syncthreads();
    int deg = cnt[t];
    int pdeg = (deg + 7) & ~7;
    scn[t] = pdeg;
    __syncthreads();
    for (int d = 1; d < 256; d <<= 1) {
        int a = (t >= d) ? scn[t - d] : 0;
        __syncthreads();
        scn[t] += a;
        __syncthreads();
    }
    int beg = b * CAP_S + scn[t] - pdeg;
    int node = b * 256 + t;
    if (node < N_NODES) {
        offs2[node] = make_int2(beg, beg + pdeg);
        dinv[node] = rsqrtf(1.0f + (float)deg);
    }
    cur[t] = beg;
    __syncthreads();
    for (int e = t; e < m; e += 256) {
        unsigned int pk = tp[e];
        int p = atomicAdd(&cur[pk >> 17], 1);
        sorted[p] = (int)(pk & 0x1FFFFu);
    }
    __syncthreads();
    int ce = cur[t];                        // beg + deg
    for (int p = ce; p < beg + pdeg; ++p) sorted[p] = SENT;
}

// ---- GEMM layer 1: xs8 = fp8((X @ W1) * dinv[row]), K=128 ----
__global__ __launch_bounds__(256) void gemm1(const float* __restrict__ X, const float* __restrict__ W,
                                             const float* __restrict__ dinv, unsigned int* __restrict__ xs8) {
    __shared__ float sW[128 * 64];
    __shared__ float sX[16 * 132];
    int tid = threadIdx.x;
    {
        const float4* ws = (const float4*)W;
        float4* wd = (float4*)sW;
        for (int i = tid; i < 2048; i += 256) wd[i] = ws[i];
    }
    int row0 = blockIdx.x * 16;
    {
        const float4* xs = (const float4*)(X + row0 * 128);
        for (int i = tid; i < 512; i += 256) {
            int r = i >> 5, q = i & 31;
            *(float4*)&sX[r * 132 + 4 * q] = xs[r * 32 + q];
        }
    }
    __syncthreads();
    int r = tid >> 4;
    int cg = (tid & 15) * 4;
    int row = row0 + r;
    float a0 = 0, a1 = 0, a2 = 0, a3 = 0;
#pragma unroll 8
    for (int k = 0; k < 128; ++k) {
        float xv = sX[r * 132 + k];
        float4 w = *(const float4*)&sW[k * 64 + cg];
        a0 += xv * w.x; a1 += xv * w.y; a2 += xv * w.z; a3 += xv * w.w;
    }
    float s = dinv[row];
    unsigned int pk = 0;
    pk = __builtin_amdgcn_cvt_pk_fp8_f32(a0 * s, a1 * s, pk, false);
    pk = __builtin_amdgcn_cvt_pk_fp8_f32(a2 * s, a3 * s, pk, true);
    xs8[row * 16 + (cg >> 2)] = pk;
}

// ---- GEMM layer 2: xs8 = fp8((h1 @ W2) * dinv[row]), K=64 ----
__global__ __launch_bounds__(256) void gemm2(const float* __restrict__ X, const float* __restrict__ W,
                                             const float* __restrict__ dinv, unsigned int* __restrict__ xs8) {
    __shared__ float sW[64 * 64];
    __shared__ float sX[16][65];
    int tid = threadIdx.x;
    for (int i = tid; i < 64 * 64; i += 256) sW[i] = W[i];
    int row0 = blockIdx.x * 16;
    for (int i = tid; i < 16 * 64; i += 256) {
        int r = i >> 6, k = i & 63;
        sX[r][k] = X[(row0 + r) * 64 + k];
    }
    __syncthreads();
    int r = tid >> 4;
    int cg = (tid & 15) * 4;
    int row = row0 + r;
    float a0 = 0, a1 = 0, a2 = 0, a3 = 0;
#pragma unroll 8
    for (int k = 0; k < 64; ++k) {
        float xv = sX[r][k];
        float4 w = *(const float4*)&sW[k * 64 + cg];
        a0 += xv * w.x; a1 += xv * w.y; a2 += xv * w.z; a3 += xv * w.w;
    }
    float s = dinv[row];
    unsigned int pk = 0;
    pk = __builtin_amdgcn_cvt_pk_fp8_f32(a0 * s, a1 * s, pk, false);
    pk = __builtin_amdgcn_cvt_pk_fp8_f32(a2 * s, a3 * s, pk, true);
    xs8[row * 16 + (cg >> 2)] = pk;
}

// ---- multi-node streaming gather (fp8 rows, 64B each) ----
#define ADD_ROW(rv) { \
    v2f f0 = __builtin_amdgcn_cvt_pk_f32_fp8((rv).x, false); \
    v2f f1 = __builtin_amdgcn_cvt_pk_f32_fp8((rv).x, true); \
    v2f f2 = __builtin_amdgcn_cvt_pk_f32_fp8((rv).y, false); \
    v2f f3 = __builtin_amdgcn_cvt_pk_f32_fp8((rv).y, true); \
    a0 += f0.x; a1 += f0.y; a2 += f1.x; a3 += f1.y; \
    a4 += f2.x; a5 += f2.y; a6 += f3.x; a7 += f3.y; }

__global__ __launch_bounds__(256) void gather_m(const unsigned char* __restrict__ xs8,
                                                const int2* __restrict__ offs2,
                                                const int* __restrict__ sorted,
                                                const float* __restrict__ dinv,
                                                const float* __restrict__ bias,
                                                float* __restrict__ fout) {
    int wv = blockIdx.x * 4 + (threadIdx.x >> 6);  // 12500 waves, 4 nodes each (same bucket)
    int lane = threadIdx.x & 63;
    int sub = lane >> 3, frag = lane & 7;
    int n0 = wv * 4;
    int2 oe = offs2[n0 + (lane < 4 ? lane : 3)];
    int e0 = __shfl(oe.x, 0), e1 = __shfl(oe.x, 1), e2 = __shfl(oe.x, 2);
    int e3 = __shfl(oe.x, 3), e4 = __shfl(oe.y, 3);
    int G   = (e4 - e0) >> 3;
    int nb1 = (e1 - e0) >> 3, nb2 = (e2 - e0) >> 3, nb3 = (e3 - e0) >> 3;
    const int* sb = sorted + e0 + sub;
    int i0 = (0 < G) ? sb[0]  : SENT;
    int i1 = (1 < G) ? sb[8]  : SENT;
    int i2 = (2 < G) ? sb[16] : SENT;
    int i3 = (3 < G) ? sb[24] : SENT;
    float4 bA = *(const float4*)(bias + frag * 8);
    float4 bB = *(const float4*)(bias + frag * 8 + 4);
    int cur = 0;
    uint2 sv = *(const uint2*)(xs8 + n0 * 64 + frag * 8);
    float dv = dinv[n0];
    float a0 = 0, a1 = 0, a2 = 0, a3 = 0, a4 = 0, a5 = 0, a6 = 0, a7 = 0;

#define FLUSH_ADV() { \
    if (sub == 0) ADD_ROW(sv); \
    a0 += __shfl_xor(a0, 8);  a1 += __shfl_xor(a1, 8);  a2 += __shfl_xor(a2, 8);  a3 += __shfl_xor(a3, 8); \
    a4 += __shfl_xor(a4, 8);  a5 += __shfl_xor(a5, 8);  a6 += __shfl_xor(a6, 8);  a7 += __shfl_xor(a7, 8); \
    a0 += __shfl_xor(a0, 16); a1 += __shfl_xor(a1, 16); a2 += __shfl_xor(a2, 16); a3 += __shfl_xor(a3, 16); \
    a4 += __shfl_xor(a4, 16); a5 += __shfl_xor(a5, 16); a6 += __shfl_xor(a6, 16); a7 += __shfl_xor(a7, 16); \
    a0 += __shfl_xor(a0, 32); a1 += __shfl_xor(a1, 32); a2 += __shfl_xor(a2, 32); a3 += __shfl_xor(a3, 32); \
    a4 += __shfl_xor(a4, 32); a5 += __shfl_xor(a5, 32); a6 += __shfl_xor(a6, 32); a7 += __shfl_xor(a7, 32); \
    if (sub == 0) { \
        float4 w0, w1; \
        w0.x = fmaxf(a0 * dv + bA.x, 0.0f); w0.y = fmaxf(a1 * dv + bA.y, 0.0f); \
        w0.z = fmaxf(a2 * dv + bA.z, 0.0f); w0.w = fmaxf(a3 * dv + bA.w, 0.0f); \
        w1.x = fmaxf(a4 * dv + bB.x, 0.0f); w1.y = fmaxf(a5 * dv + bB.y, 0.0f); \
        w1.z = fmaxf(a6 * dv + bB.z, 0.0f); w1.w = fmaxf(a7 * dv + bB.w, 0.0f); \
        float* o = fout + (n0 + cur) * 64 + frag * 8; \
        *(float4*)(o) = w0; *(float4*)(o + 4) = w1; \
    } \
    a0 = a1 = a2 = a3 = a4 = a5 = a6 = a7 = 0.0f; \
    cur++; \
    if (cur < 4) { \
        sv = *(const uint2*)(xs8 + (n0 + cur) * 64 + frag * 8); \
        dv = dinv[n0 + cur]; \
    } }

#define BND_NXT() (cur == 0 ? nb1 : cur == 1 ? nb2 : cur == 2 ? nb3 : G)

    for (int g = 0; g < G; g += 4) {
        uint2 r0 = *(const uint2*)(xs8 + i0 * 64 + frag * 8);
        uint2 r1 = *(const uint2*)(xs8 + i1 * 64 + frag * 8);
        uint2 r2 = *(const uint2*)(xs8 + i2 * 64 + frag * 8);
        uint2 r3 = *(const uint2*)(xs8 + i3 * 64 + frag * 8);
        const int* np = sb + (g + 4) * 8;
        i0 = (g + 4 < G) ? np[0]  : SENT;
        i1 = (g + 5 < G) ? np[8]  : SENT;
        i2 = (g + 6 < G) ? np[16] : SENT;
        i3 = (g + 7 < G) ? np[24] : SENT;
        {   int gg = g;
            int nxt = BND_NXT();
            while (cur < 4 && gg >= nxt) { FLUSH_ADV(); nxt = BND_NXT(); }
            ADD_ROW(r0); }
        if (g + 1 < G) {
            int gg = g + 1;
            int nxt = BND_NXT();
            while (cur < 4 && gg >= nxt) { FLUSH_ADV(); nxt = BND_NXT(); }
            ADD_ROW(r1);
        }
        if (g + 2 < G) {
            int gg = g + 2;
            int nxt = BND_NXT();
            while (cur < 4 && gg >= nxt) { FLUSH_ADV(); nxt = BND_NXT(); }
            ADD_ROW(r2);
        }
        if (g + 3 < G) {
            int gg = g + 3;
            int nxt = BND_NXT();
            while (cur < 4 && gg >= nxt) { FLUSH_ADV(); nxt = BND_NXT(); }
            ADD_ROW(r3);
        }
    }
    while (cur < 4) { FLUSH_ADV(); }
#undef FLUSH_ADV
#undef BND_NXT
}

// ---- fused pool (segmented mean over sorted batch) + fc head + log_softmax ----
__device__ __forceinline__ int lower_bound(const int* __restrict__ a, int n, int v) {
    int lo = 0, hi = n;
    while (lo < hi) { int m = (lo + hi) >> 1; if (a[m] < v) lo = m + 1; else hi = m; }
    return lo;
}

__global__ __launch_bounds__(256) void pool_head(const float* __restrict__ h2,
                                                 const int* __restrict__ batch,
                                                 const float* __restrict__ Wfc, const float* __restrict__ bfc,
                                                 const int* __restrict__ y, float* __restrict__ out) {
    __shared__ int s_beg, s_end;
    __shared__ float sh[4][64];
    __shared__ float pl[64];
    __shared__ float lg[4];
    int g = blockIdx.x;
    int t = threadIdx.x;
    if (t == 0) s_beg = lower_bound(batch, N_NODES, g);
    if (t == 1) s_end = lower_bound(batch, N_NODES, g + 1);
    __syncthreads();
    int beg = s_beg, end = s_end;
    int f = t & 63, seg = t >> 6;
    float s = 0.0f;
    for (int r = beg + seg; r < end; r += 4) s += h2[r * 64 + f];
    sh[seg][f] = s;
    __syncthreads();
    if (t < 64) {
        float p = sh[0][t] + sh[1][t] + sh[2][t] + sh[3][t];
        pl[t] = p / fmaxf((float)(end - beg), 1.0f);
    }
    __syncthreads();
    if (t < 4) {
        float l = bfc[t];
#pragma unroll
        for (int k = 0; k < 64; ++k) l += pl[k] * Wfc[k * 4 + t];
        lg[t] = l;
    }
    __syncthreads();
    if (t == 0) {
        float l0 = lg[0], l1 = lg[1], l2 = lg[2], l3 = lg[3];
        float m = fmaxf(fmaxf(l0, l1), fmaxf(l2, l3));
        float ss = expf(l0 - m) + expf(l1 - m) + expf(l2 - m) + expf(l3 - m);
        float lse = m + logf(ss);
        out[g * 4 + 0] = l0 - lse;
        out[g * 4 + 1] = l1 - lse;
        out[g * 4 + 2] = l2 - lse;
        out[g * 4 + 3] = l3 - lse;
        out[N_GRAPHS * 4 + g] = (float)y[g];
    }
}

extern "C" void kernel_launch(void* const* d_in, const int* in_sizes, int n_in,
                              void* d_out, int out_size, void* d_ws, size_t ws_size,
                              hipStream_t stream) {
    const float* x     = (const float*)d_in[0];
    const int*   ei    = (const int*)d_in[1];
    const int*   batch = (const int*)d_in[2];
    const int*   y     = (const int*)d_in[3];
    const float* W1    = (const float*)d_in[4];
    const float* b1    = (const float*)d_in[5];
    const float* W2    = (const float*)d_in[6];
    const float* b2    = (const float*)d_in[7];
    const float* Wfc   = (const float*)d_in[8];
    const float* bfc   = (const float*)d_in[9];
    float* out = (float*)d_out;

    const int* src = ei;
    const int* dst = ei + N_EDGES;

    char* wsb = (char*)d_ws;
    int*          bcnt   = (int*)(wsb + OFF_BCNT);
    float*        dinv   = (float*)(wsb + OFF_DINV);
    int2*         offs2  = (int2*)(wsb + OFF_OFFS2);
    unsigned int* tmp    = (unsigned int*)(wsb + OFF_TMP);
    int*          sorted = (int*)(wsb + OFF_SORTED);
    unsigned int* xs8_1  = (unsigned int*)(wsb + OFF_XS8_1);
    unsigned int* xs8_2  = (unsigned int*)(wsb + OFF_XS8_2);
    float*        hbuf   = (float*)(wsb + OFF_HBUF);

    hipMemsetAsync(bcnt, 0, 1024u, stream);

    binA<<<NBKT, 256, 0, stream>>>(src, dst, bcnt, tmp, xs8_1, xs8_2);
    binB2<<<NBKT, 256, 0, stream>>>(tmp, bcnt, sorted, offs2, dinv);

    // layer 1: 128 -> 64
    gemm1<<<N_NODES / 16, 256, 0, stream>>>(x, W1, dinv, xs8_1);
    gather_m<<<N_NODES / 16, 256, 0, stream>>>((const unsigned char*)xs8_1, offs2, sorted, dinv, b1, hbuf);
    // layer 2: 64 -> 64
    gemm2<<<N_NODES / 16, 256, 0, stream>>>(hbuf, W2, dinv, xs8_2);
    gather_m<<<N_NODES / 16, 256, 0, stream>>>((const unsigned char*)xs8_2, offs2, sorted, dinv, b2, hbuf);

    pool_head<<<N_GRAPHS, 256, 0, stream>>>(hbuf, batch, Wfc, bfc, y, out);
}